// Round 1
// baseline (16.510 us; speedup 1.0000x reference)
//
#include <hip/hip_runtime.h>
#include <hip/hip_bf16.h>

// out[n][c] = -sum_f (x[n][f]-m[c][f])^2 = 2*x.m - |x|^2 - |m|^2
// N=2048 samples, C=512 classes, F=512 features, fp32 in/out.

#define N_ROWS 2048
#define C_ROWS 512
#define F_DIM  512

typedef __attribute__((ext_vector_type(8))) short short8;
typedef __attribute__((ext_vector_type(4))) float f32x4;

static __device__ __forceinline__ short f2bf_rne(float f) {
    unsigned u = __builtin_bit_cast(unsigned, f);
    unsigned r = (u + 0x7fffu + ((u >> 16) & 1u)) >> 16;
    return (short)r;
}

// One wave per row: convert fp32 row -> bf16 (workspace) and compute fp32 ||row||^2.
// Rows 0..2047 = x, rows 2048..2559 = means.
__global__ __launch_bounds__(256) void prep_kernel(
        const float* __restrict__ x, const float* __restrict__ means,
        short* __restrict__ xb, short* __restrict__ mb,
        float* __restrict__ xnorm, float* __restrict__ mnorm) {
    const int w    = threadIdx.x >> 6;
    const int lane = threadIdx.x & 63;
    const int row  = blockIdx.x * 4 + w;

    const float* src;
    short* dst;
    float* nrm;
    if (row < N_ROWS) {
        src = x + (size_t)row * F_DIM;
        dst = xb + (size_t)row * F_DIM;
        nrm = xnorm + row;
    } else {
        const int r = row - N_ROWS;
        src = means + (size_t)r * F_DIM;
        dst = mb + (size_t)r * F_DIM;
        nrm = mnorm + r;
    }

    float4 v0 = *(const float4*)(src + lane * 8);
    float4 v1 = *(const float4*)(src + lane * 8 + 4);
    float vals[8] = {v0.x, v0.y, v0.z, v0.w, v1.x, v1.y, v1.z, v1.w};

    short8 o;
    float ss = 0.f;
#pragma unroll
    for (int j = 0; j < 8; j++) {
        ss += vals[j] * vals[j];
        o[j] = f2bf_rne(vals[j]);
    }
    *(short8*)(dst + lane * 8) = o;

#pragma unroll
    for (int off = 32; off > 0; off >>= 1) ss += __shfl_xor(ss, off);
    if (lane == 0) *nrm = ss;
}

// 64x64 output tile per block (grid 32x8 = 256 blocks), BK=64, 4 waves (2x2),
// each wave owns a 32x32 sub-tile (2x2 fragments of 16x16x32 bf16 MFMA).
// LDS tiles [64 rows][64 bf16] = 128B row stride; XOR-swizzle 16B slots within
// each row by (row&7) to kill the 16-way ds_read_b128 bank conflict.
// global_load_lds writes linearly, so the SOURCE global chunk is pre-swizzled
// (rule #21: both-sides-or-neither).
__global__ __launch_bounds__(256) void nsq_mfma(
        const short* __restrict__ xb, const short* __restrict__ mb,
        const float* __restrict__ xnorm, const float* __restrict__ mnorm,
        float* __restrict__ out) {
    __shared__ __align__(16) short lds[2 * 64 * 64];  // A then B, 16 KiB
    short* As = lds;
    short* Bs = lds + 64 * 64;

    const int t    = threadIdx.x;
    const int w    = t >> 6;
    const int lane = t & 63;
    const int rowBase = blockIdx.x * 64;
    const int colBase = blockIdx.y * 64;
    const int wRow = (w >> 1) * 32;
    const int wCol = (w & 1) * 32;

    f32x4 acc[2][2];
#pragma unroll
    for (int mi = 0; mi < 2; mi++)
#pragma unroll
        for (int ni = 0; ni < 2; ni++)
            acc[mi][ni] = (f32x4){0.f, 0.f, 0.f, 0.f};

    const int srow  = t >> 3;  // 0..31: row within 32-row chunk per issue
    const int sslot = t & 7;   // 16B slot within 128B row

    for (int k0 = 0; k0 < F_DIM; k0 += 64) {
        __syncthreads();  // prior iteration's reads done before overwrite
#pragma unroll
        for (int i = 0; i < 2; i++) {
            const int r  = i * 32 + srow;
            const int sc = sslot ^ (r & 7);  // pre-swizzled source chunk
            const short* ga = xb + (size_t)(rowBase + r) * F_DIM + k0 + sc * 8;
            const short* gb = mb + (size_t)(colBase + r) * F_DIM + k0 + sc * 8;
            short* la = As + i * 2048 + w * 512;  // wave-uniform LDS base
            short* lb = Bs + i * 2048 + w * 512;
            __builtin_amdgcn_global_load_lds(
                (const __attribute__((address_space(1))) void*)ga,
                (__attribute__((address_space(3))) void*)la, 16, 0, 0);
            __builtin_amdgcn_global_load_lds(
                (const __attribute__((address_space(1))) void*)gb,
                (__attribute__((address_space(3))) void*)lb, 16, 0, 0);
        }
        __syncthreads();  // drains vmcnt: tiles ready

#pragma unroll
        for (int kk = 0; kk < 2; kk++) {
            short8 a[2], b[2];
#pragma unroll
            for (int mi = 0; mi < 2; mi++) {
                const int r    = wRow + mi * 16 + (lane & 15);
                const int slot = kk * 4 + (lane >> 4);
                a[mi] = *(const short8*)(As + r * 64 + ((slot ^ (r & 7)) * 8));
            }
#pragma unroll
            for (int ni = 0; ni < 2; ni++) {
                const int r    = wCol + ni * 16 + (lane & 15);
                const int slot = kk * 4 + (lane >> 4);
                b[ni] = *(const short8*)(Bs + r * 64 + ((slot ^ (r & 7)) * 8));
            }
#pragma unroll
            for (int mi = 0; mi < 2; mi++)
#pragma unroll
                for (int ni = 0; ni < 2; ni++)
                    acc[mi][ni] = __builtin_amdgcn_mfma_f32_16x16x32_bf16(
                        a[mi], b[ni], acc[mi][ni], 0, 0, 0);
        }
    }

    // Epilogue: out = 2*acc - xnorm - mnorm.
    // C/D layout (verified m89/m91): col = lane&15, row = (lane>>4)*4 + j.
    float xn[2][4];
#pragma unroll
    for (int mi = 0; mi < 2; mi++)
#pragma unroll
        for (int j = 0; j < 4; j++)
            xn[mi][j] = xnorm[rowBase + wRow + mi * 16 + (lane >> 4) * 4 + j];

#pragma unroll
    for (int ni = 0; ni < 2; ni++) {
        const int c = colBase + wCol + ni * 16 + (lane & 15);
        const float mn = mnorm[c];
#pragma unroll
        for (int mi = 0; mi < 2; mi++) {
            const int rbase = rowBase + wRow + mi * 16 + (lane >> 4) * 4;
#pragma unroll
            for (int j = 0; j < 4; j++)
                out[(size_t)(rbase + j) * C_ROWS + c] =
                    2.0f * acc[mi][ni][j] - xn[mi][j] - mn;
        }
    }
}

// Safety-net direct fp32 kernel (only used if workspace is too small).
__global__ __launch_bounds__(256) void fallback_kernel(
        const float* __restrict__ x, const float* __restrict__ means,
        float* __restrict__ out) {
    __shared__ float xrow[F_DIM];
    const int n = blockIdx.x;
    const int c = blockIdx.y * 256 + threadIdx.x;
    for (int f = threadIdx.x; f < F_DIM; f += 256) xrow[f] = x[(size_t)n * F_DIM + f];
    __syncthreads();
    const float* m = means + (size_t)c * F_DIM;
    float s = 0.f;
    for (int f = 0; f < F_DIM; f++) {
        float d = xrow[f] - m[f];
        s += d * d;
    }
    out[(size_t)n * C_ROWS + c] = -s;
}

extern "C" void kernel_launch(void* const* d_in, const int* in_sizes, int n_in,
                              void* d_out, int out_size, void* d_ws, size_t ws_size,
                              hipStream_t stream) {
    const float* x     = (const float*)d_in[0];
    const float* means = (const float*)d_in[1];
    float* out = (float*)d_out;

    const size_t need = (size_t)N_ROWS * F_DIM * 2 + (size_t)C_ROWS * F_DIM * 2 +
                        (size_t)N_ROWS * 4 + (size_t)C_ROWS * 4;
    if (ws_size >= need) {
        short* xb = (short*)d_ws;
        short* mb = xb + (size_t)N_ROWS * F_DIM;
        float* xnorm = (float*)(mb + (size_t)C_ROWS * F_DIM);
        float* mnorm = xnorm + N_ROWS;

        prep_kernel<<<(N_ROWS + C_ROWS) / 4, 256, 0, stream>>>(x, means, xb, mb, xnorm, mnorm);
        dim3 grid(N_ROWS / 64, C_ROWS / 64);
        nsq_mfma<<<grid, 256, 0, stream>>>(xb, mb, xnorm, mnorm, out);
    } else {
        dim3 grid(N_ROWS, C_ROWS / 256);
        fallback_kernel<<<grid, 256, 0, stream>>>(x, means, out);
    }
}

// Round 2
// 15.389 us; speedup vs baseline: 1.0729x; 1.0729x over previous
//
#include <hip/hip_runtime.h>
#include <hip/hip_bf16.h>

// out[n][c] = -sum_f (x[n][f]-m[c][f])^2 = 2*x.m - |x|^2 - |m|^2
// N=2048 samples, C=512 classes, F=512 features, fp32 in/out.
// Kernel 1 (prep): fp32 -> bf16 conversion + fp32 row norms.
// Kernel 2 (nsq_mfma): bf16 MFMA GEMM (cross term), fused -|x|^2-|m|^2 epilogue.

#define N_ROWS 2048
#define C_ROWS 512
#define F_DIM  512

typedef __attribute__((ext_vector_type(8))) short short8;
typedef __attribute__((ext_vector_type(4))) float f32x4;

static __device__ __forceinline__ short f2bf_rne(float f) {
    unsigned u = __builtin_bit_cast(unsigned, f);
    unsigned r = (u + 0x7fffu + ((u >> 16) & 1u)) >> 16;
    return (short)r;
}

// One wave per row: convert fp32 row -> bf16 (workspace) and compute fp32 ||row||^2.
// Rows 0..2047 = x, rows 2048..2559 = means.
__global__ __launch_bounds__(256) void prep_kernel(
        const float* __restrict__ x, const float* __restrict__ means,
        short* __restrict__ xb, short* __restrict__ mb,
        float* __restrict__ xnorm, float* __restrict__ mnorm) {
    const int w    = threadIdx.x >> 6;
    const int lane = threadIdx.x & 63;
    const int row  = blockIdx.x * 4 + w;

    const float* src;
    short* dst;
    float* nrm;
    if (row < N_ROWS) {
        src = x + (size_t)row * F_DIM;
        dst = xb + (size_t)row * F_DIM;
        nrm = xnorm + row;
    } else {
        const int r = row - N_ROWS;
        src = means + (size_t)r * F_DIM;
        dst = mb + (size_t)r * F_DIM;
        nrm = mnorm + r;
    }

    float4 v0 = *(const float4*)(src + lane * 8);
    float4 v1 = *(const float4*)(src + lane * 8 + 4);
    float vals[8] = {v0.x, v0.y, v0.z, v0.w, v1.x, v1.y, v1.z, v1.w};

    short8 o;
    float ss = 0.f;
#pragma unroll
    for (int j = 0; j < 8; j++) {
        ss += vals[j] * vals[j];
        o[j] = f2bf_rne(vals[j]);
    }
    *(short8*)(dst + lane * 8) = o;

#pragma unroll
    for (int off = 32; off > 0; off >>= 1) ss += __shfl_xor(ss, off);
    if (lane == 0) *nrm = ss;
}

// 64x32 output tile per block, 128 threads (2 waves, each a 32x32 sub-tile).
// Grid (32,16) = 512 blocks -> 2 blocks/CU for TLP. BK=64, double-buffered
// LDS with a single __syncthreads per K-iter (implicit vmcnt(0) is the
// pipeline fence): stage(next) is issued BEFORE compute(cur) so global
// latency hides under ds_read+MFMA.
// LDS row stride = 64 bf16 = 128 B; 16B slots XOR-swizzled by (row&7).
// global_load_lds writes linearly, so the SOURCE global chunk is
// pre-swizzled (both-sides-or-neither, rule #21).
__global__ __launch_bounds__(128) void nsq_mfma(
        const short* __restrict__ xb, const short* __restrict__ mb,
        const float* __restrict__ xnorm, const float* __restrict__ mnorm,
        float* __restrict__ out) {
    // per buffer: A 64x64 bf16 (4096 shorts) + B 32x64 bf16 (2048 shorts)
    __shared__ __align__(16) short lds[2 * 6144];

    const int t    = threadIdx.x;
    const int w    = t >> 6;
    const int lane = t & 63;
    const int rowBase = blockIdx.x * 64;
    const int colBase = blockIdx.y * 32;

    const int srow  = t >> 3;  // 0..15
    const int sslot = t & 7;

    f32x4 acc[2][2];
#pragma unroll
    for (int mi = 0; mi < 2; mi++)
#pragma unroll
        for (int ni = 0; ni < 2; ni++)
            acc[mi][ni] = (f32x4){0.f, 0.f, 0.f, 0.f};

    auto stage = [&](int buf, int k0) {
        short* As = lds + buf * 6144;
        short* Bs = As + 4096;
        // A: 64 rows in 4 chunks of 16
#pragma unroll
        for (int i = 0; i < 4; i++) {
            const int r  = i * 16 + srow;
            const int sc = sslot ^ (r & 7);
            const short* ga = xb + (size_t)(rowBase + r) * F_DIM + k0 + sc * 8;
            short* la = As + i * 1024 + w * 512;  // wave-uniform base; +lane*16B is linear
            __builtin_amdgcn_global_load_lds(
                (const __attribute__((address_space(1))) void*)ga,
                (__attribute__((address_space(3))) void*)la, 16, 0, 0);
        }
        // B: 32 rows in 2 chunks of 16
#pragma unroll
        for (int i = 0; i < 2; i++) {
            const int r  = i * 16 + srow;
            const int sc = sslot ^ (r & 7);
            const short* gb = mb + (size_t)(colBase + r) * F_DIM + k0 + sc * 8;
            short* lb = Bs + i * 1024 + w * 512;
            __builtin_amdgcn_global_load_lds(
                (const __attribute__((address_space(1))) void*)gb,
                (__attribute__((address_space(3))) void*)lb, 16, 0, 0);
        }
    };

    auto compute = [&](int buf) {
        const short* As = lds + buf * 6144;
        const short* Bs = As + 4096;
#pragma unroll
        for (int kk = 0; kk < 2; kk++) {
            const int slot = kk * 4 + (lane >> 4);
            short8 a[2], b[2];
#pragma unroll
            for (int mi = 0; mi < 2; mi++) {
                const int r = w * 32 + mi * 16 + (lane & 15);
                a[mi] = *(const short8*)(As + r * 64 + ((slot ^ (r & 7)) * 8));
            }
#pragma unroll
            for (int ni = 0; ni < 2; ni++) {
                const int r = ni * 16 + (lane & 15);
                b[ni] = *(const short8*)(Bs + r * 64 + ((slot ^ (r & 7)) * 8));
            }
#pragma unroll
            for (int mi = 0; mi < 2; mi++)
#pragma unroll
                for (int ni = 0; ni < 2; ni++)
                    acc[mi][ni] = __builtin_amdgcn_mfma_f32_16x16x32_bf16(
                        a[mi], b[ni], acc[mi][ni], 0, 0, 0);
        }
    };

    // Pipelined K loop: 8 tiles of BK=64.
    stage(0, 0);
    __syncthreads();
    int cur = 0;
#pragma unroll
    for (int it = 0; it < 7; it++) {
        stage(cur ^ 1, (it + 1) * 64);
        compute(cur);
        __syncthreads();  // vmcnt(0): next tile staged; lgkm drained
        cur ^= 1;
    }
    compute(cur);

    // Epilogue: out = 2*acc - xnorm - mnorm.
    // C/D layout: col = lane&15, row = (lane>>4)*4 + j.
    float xn[2][4];
#pragma unroll
    for (int mi = 0; mi < 2; mi++)
#pragma unroll
        for (int j = 0; j < 4; j++)
            xn[mi][j] = xnorm[rowBase + w * 32 + mi * 16 + (lane >> 4) * 4 + j];

#pragma unroll
    for (int ni = 0; ni < 2; ni++) {
        const int c = colBase + ni * 16 + (lane & 15);
        const float mn = mnorm[c];
#pragma unroll
        for (int mi = 0; mi < 2; mi++) {
            const int rbase = rowBase + w * 32 + mi * 16 + (lane >> 4) * 4;
#pragma unroll
            for (int j = 0; j < 4; j++)
                out[(size_t)(rbase + j) * C_ROWS + c] =
                    2.0f * acc[mi][ni][j] - xn[mi][j] - mn;
        }
    }
}

// Safety-net direct fp32 kernel (only used if workspace is too small).
__global__ __launch_bounds__(256) void fallback_kernel(
        const float* __restrict__ x, const float* __restrict__ means,
        float* __restrict__ out) {
    __shared__ float xrow[F_DIM];
    const int n = blockIdx.x;
    const int c = blockIdx.y * 256 + threadIdx.x;
    for (int f = threadIdx.x; f < F_DIM; f += 256) xrow[f] = x[(size_t)n * F_DIM + f];
    __syncthreads();
    const float* m = means + (size_t)c * F_DIM;
    float s = 0.f;
    for (int f = 0; f < F_DIM; f++) {
        float d = xrow[f] - m[f];
        s += d * d;
    }
    out[(size_t)n * C_ROWS + c] = -s;
}

extern "C" void kernel_launch(void* const* d_in, const int* in_sizes, int n_in,
                              void* d_out, int out_size, void* d_ws, size_t ws_size,
                              hipStream_t stream) {
    const float* x     = (const float*)d_in[0];
    const float* means = (const float*)d_in[1];
    float* out = (float*)d_out;

    const size_t need = (size_t)N_ROWS * F_DIM * 2 + (size_t)C_ROWS * F_DIM * 2 +
                        (size_t)N_ROWS * 4 + (size_t)C_ROWS * 4;
    if (ws_size >= need) {
        short* xb = (short*)d_ws;
        short* mb = xb + (size_t)N_ROWS * F_DIM;
        float* xnorm = (float*)(mb + (size_t)C_ROWS * F_DIM);
        float* mnorm = xnorm + N_ROWS;

        prep_kernel<<<(N_ROWS + C_ROWS) / 4, 256, 0, stream>>>(x, means, xb, mb, xnorm, mnorm);
        dim3 grid(N_ROWS / 64, C_ROWS / 32);
        nsq_mfma<<<grid, 128, 0, stream>>>(xb, mb, xnorm, mnorm, out);
    } else {
        dim3 grid(N_ROWS, C_ROWS / 256);
        fallback_kernel<<<grid, 256, 0, stream>>>(x, means, out);
    }
}

// Round 3
// 12.988 us; speedup vs baseline: 1.2712x; 1.1848x over previous
//
#include <hip/hip_runtime.h>
#include <hip/hip_bf16.h>

// out[n][c] = -sum_f (x[n][f]-m[c][f])^2 = 2*x.m - |x|^2 - |m|^2
// N=2048, C=512, F=512, fp32 in/out.
//
// SINGLE fused kernel (no workspace, one launch): each block owns a 64x64
// output tile with full K=512 in LDS (A 64KB + B 64KB bf16). Phase 1 stages
// fp32 rows -> bf16 LDS (XOR-swizzled ds_write_b128) and computes exact fp32
// row norms in the same pass. Phase 2: 16 MFMA K-steps. Epilogue fuses
// 2*acc - |x|^2 - |m|^2.

#define F_DIM  512
#define C_ROWS 512

typedef __attribute__((ext_vector_type(8))) short short8;
typedef __attribute__((ext_vector_type(4))) float f32x4;

static __device__ __forceinline__ short f2bf_rne(float f) {
    unsigned u = __builtin_bit_cast(unsigned, f);
    unsigned r = (u + 0x7fffu + ((u >> 16) & 1u)) >> 16;
    return (short)r;
}

__global__ __launch_bounds__(256) void ncm_fused(
        const float* __restrict__ x, const float* __restrict__ means,
        float* __restrict__ out) {
    // 64 rows x 512 bf16 each; row stride 1024B. 16B slots XOR-swizzled by
    // (row&7) on BOTH write (ds_write_b128) and read (ds_read_b128) sides.
    __shared__ __align__(16) short As[64 * 512];
    __shared__ __align__(16) short Bs[64 * 512];
    __shared__ float xn_s[64], mn_s[64];

    // Block -> tile mapping: XCD (d&7) owns 4 consecutive row-tiles so its L2
    // working set is 512KB of x + 1MB of means (both fit 4MB/XCD L2).
    const int d  = blockIdx.x;          // 0..255, 1 block/CU
    const int by = (d & 7) * 4 + ((d >> 3) & 3);  // 0..31
    const int bx = d >> 5;                         // 0..7
    const int rowBase = by * 64, colBase = bx * 64;

    const int t    = threadIdx.x;
    const int w    = t >> 6;
    const int lane = t & 63;
    const int qr   = lane >> 4;   // quarter-wave index: row offset within group
    const int ql   = lane & 15;   // lane within quarter-wave

    // ---------------- Phase 1: stage + convert + norms ----------------
    // Each wave stages 16 rows of A then 16 rows of B. Quarter-wave owns a
    // row: per (group i, phase ph) a lane covers 8 contiguous floats, so the
    // bf16 pack is a single swizzled ds_write_b128. Norm reduce = 4 shfl_xor
    // within 16 lanes (reduces 4 rows simultaneously).
#pragma unroll
    for (int half = 0; half < 2; half++) {
        const float* src = (half == 0) ? x + (size_t)rowBase * F_DIM
                                       : means + (size_t)colBase * F_DIM;
        short* dst = (half == 0) ? As : Bs;
        float* nrm = (half == 0) ? xn_s : mn_s;

        // Batch ALL 32 float4 loads for this half first (128 VGPR), so the
        // global latency is exposed once, not per-row.
        float4 va[4][4][2];
#pragma unroll
        for (int i = 0; i < 4; i++) {
            const int r = w * 16 + i * 4 + qr;
            const float* rowp = src + (size_t)r * F_DIM;
#pragma unroll
            for (int ph = 0; ph < 4; ph++) {
                const float* p = rowp + ph * 128 + ql * 8;
                va[i][ph][0] = *(const float4*)p;
                va[i][ph][1] = *(const float4*)(p + 4);
            }
        }
#pragma unroll
        for (int i = 0; i < 4; i++) {
            const int r = w * 16 + i * 4 + qr;
            float ss = 0.f;
#pragma unroll
            for (int ph = 0; ph < 4; ph++) {
                float vv[8] = {va[i][ph][0].x, va[i][ph][0].y,
                               va[i][ph][0].z, va[i][ph][0].w,
                               va[i][ph][1].x, va[i][ph][1].y,
                               va[i][ph][1].z, va[i][ph][1].w};
                short8 o;
#pragma unroll
                for (int j = 0; j < 8; j++) {
                    ss += vv[j] * vv[j];
                    o[j] = f2bf_rne(vv[j]);
                }
                const int slot = ph * 16 + ql;  // 16B slot within the row
                *(short8*)(dst + r * F_DIM + ((slot ^ (r & 7)) << 3)) = o;
            }
            ss += __shfl_xor(ss, 1);
            ss += __shfl_xor(ss, 2);
            ss += __shfl_xor(ss, 4);
            ss += __shfl_xor(ss, 8);
            if (ql == 0) nrm[r] = ss;
        }
    }
    __syncthreads();

    // ---------------- Phase 2: MFMA sweep over K=512 ----------------
    const int wr = (w >> 1) * 32;   // wave's 32x32 sub-tile
    const int wc = (w & 1) * 32;

    f32x4 acc[2][2];
#pragma unroll
    for (int mi = 0; mi < 2; mi++)
#pragma unroll
        for (int ni = 0; ni < 2; ni++)
            acc[mi][ni] = (f32x4){0.f, 0.f, 0.f, 0.f};

#pragma unroll
    for (int kk = 0; kk < 16; kk++) {
        const int slot = kk * 4 + (lane >> 4);
        short8 a[2], b[2];
#pragma unroll
        for (int mi = 0; mi < 2; mi++) {
            const int r = wr + mi * 16 + (lane & 15);
            a[mi] = *(const short8*)(As + r * F_DIM + ((slot ^ (r & 7)) << 3));
        }
#pragma unroll
        for (int ni = 0; ni < 2; ni++) {
            const int r = wc + ni * 16 + (lane & 15);
            b[ni] = *(const short8*)(Bs + r * F_DIM + ((slot ^ (r & 7)) << 3));
        }
#pragma unroll
        for (int mi = 0; mi < 2; mi++)
#pragma unroll
            for (int ni = 0; ni < 2; ni++)
                acc[mi][ni] = __builtin_amdgcn_mfma_f32_16x16x32_bf16(
                    a[mi], b[ni], acc[mi][ni], 0, 0, 0);
    }

    // ---------------- Epilogue: out = 2*acc - |x|^2 - |m|^2 ----------------
    // C/D layout: col = lane&15, row = (lane>>4)*4 + j.
    float xn[2][4];
#pragma unroll
    for (int mi = 0; mi < 2; mi++)
#pragma unroll
        for (int j = 0; j < 4; j++)
            xn[mi][j] = xn_s[wr + mi * 16 + (lane >> 4) * 4 + j];

#pragma unroll
    for (int ni = 0; ni < 2; ni++) {
        const int cl = wc + ni * 16 + (lane & 15);
        const int c  = colBase + cl;
        const float mn = mn_s[cl];
#pragma unroll
        for (int mi = 0; mi < 2; mi++) {
            const int rbase = rowBase + wr + mi * 16 + (lane >> 4) * 4;
#pragma unroll
            for (int j = 0; j < 4; j++)
                out[(size_t)(rbase + j) * C_ROWS + c] =
                    2.0f * acc[mi][ni][j] - xn[mi][j] - mn;
        }
    }
}

extern "C" void kernel_launch(void* const* d_in, const int* in_sizes, int n_in,
                              void* d_out, int out_size, void* d_ws, size_t ws_size,
                              hipStream_t stream) {
    const float* x     = (const float*)d_in[0];
    const float* means = (const float*)d_in[1];
    float* out = (float*)d_out;
    ncm_fused<<<256, 256, 0, stream>>>(x, means, out);
}

// Round 4
// 11.483 us; speedup vs baseline: 1.4379x; 1.1311x over previous
//
#include <hip/hip_runtime.h>
#include <hip/hip_bf16.h>

// out[n][c] = -sum_f (x[n][f]-m[c][f])^2 = 2*x.m - |x|^2 - |m|^2
// N=2048, C=512, F=512, fp32 in/out.
//
// Single fused kernel, grid=256 (1 block/CU), 512 threads (8 waves -> 2
// waves/SIMD for latency hiding). 64x64 output tile, full K=512 in LDS
// (A 64KB + B 64KB bf16, XOR-swizzled). Split-K: waves 0-3 compute the four
// 32x32 quadrants over K=0..255, waves 4-7 the same quadrants over
// K=256..511; partial accs combined through a padded LDS buffer.

#define F_DIM  512
#define C_ROWS 512

typedef __attribute__((ext_vector_type(8))) short short8;
typedef __attribute__((ext_vector_type(4))) float f32x4;

static __device__ __forceinline__ short f2bf_rne(float f) {
    unsigned u = __builtin_bit_cast(unsigned, f);
    unsigned r = (u + 0x7fffu + ((u >> 16) & 1u)) >> 16;
    return (short)r;
}

__global__ __launch_bounds__(512) void ncm_fused(
        const float* __restrict__ x, const float* __restrict__ means,
        float* __restrict__ out) {
    // 64 rows x 512 bf16 each; row stride 1024B. 16B slots XOR-swizzled by
    // (row&7) on BOTH write (ds_write_b128) and read (ds_read_b128) sides.
    __shared__ __align__(16) short As[64 * 512];
    __shared__ __align__(16) short Bs[64 * 512];
    __shared__ float xn_s[64], mn_s[64];

    // Block -> tile mapping: XCD (d&7) owns 4 consecutive row-tiles so its L2
    // working set is 512KB of x + 1MB of means (fits 4MB/XCD L2).
    const int d  = blockIdx.x;                     // 0..255
    const int by = (d & 7) * 4 + ((d >> 3) & 3);   // 0..31
    const int bx = d >> 5;                         // 0..7
    const int rowBase = by * 64, colBase = bx * 64;

    const int t    = threadIdx.x;
    const int w    = t >> 6;      // 0..7
    const int lane = t & 63;
    const int qr   = lane >> 4;   // quarter-wave row offset
    const int ql   = lane & 15;   // lane within quarter-wave

    // ---------------- Phase 1: stage + convert + norms ----------------
    // Each wave stages 8 rows of A then 8 rows of B. Quarter-wave owns a row;
    // a lane covers 8 contiguous floats -> one swizzled ds_write_b128.
    // Norm reduce = 4 shfl_xor within 16 lanes (4 rows at once).
#pragma unroll
    for (int half = 0; half < 2; half++) {
        const float* src = (half == 0) ? x + (size_t)rowBase * F_DIM
                                       : means + (size_t)colBase * F_DIM;
        short* dst = (half == 0) ? As : Bs;
        float* nrm = (half == 0) ? xn_s : mn_s;

        // Batch all 16 float4 loads for this half (64 VGPR): one latency
        // exposure per half, overlapped across 2 waves/SIMD.
        float4 va[2][4][2];
#pragma unroll
        for (int i = 0; i < 2; i++) {
            const int r = w * 8 + i * 4 + qr;
            const float* rowp = src + (size_t)r * F_DIM;
#pragma unroll
            for (int ph = 0; ph < 4; ph++) {
                const float* p = rowp + ph * 128 + ql * 8;
                va[i][ph][0] = *(const float4*)p;
                va[i][ph][1] = *(const float4*)(p + 4);
            }
        }
#pragma unroll
        for (int i = 0; i < 2; i++) {
            const int r = w * 8 + i * 4 + qr;
            float ss = 0.f;
#pragma unroll
            for (int ph = 0; ph < 4; ph++) {
                float vv[8] = {va[i][ph][0].x, va[i][ph][0].y,
                               va[i][ph][0].z, va[i][ph][0].w,
                               va[i][ph][1].x, va[i][ph][1].y,
                               va[i][ph][1].z, va[i][ph][1].w};
                short8 o;
#pragma unroll
                for (int j = 0; j < 8; j++) {
                    ss += vv[j] * vv[j];
                    o[j] = f2bf_rne(vv[j]);
                }
                const int slot = ph * 16 + ql;
                *(short8*)(dst + r * F_DIM + ((slot ^ (r & 7)) << 3)) = o;
            }
            ss += __shfl_xor(ss, 1);
            ss += __shfl_xor(ss, 2);
            ss += __shfl_xor(ss, 4);
            ss += __shfl_xor(ss, 8);
            if (ql == 0) nrm[r] = ss;
        }
    }
    __syncthreads();

    // ---------------- Phase 2: MFMA, split-K across wave groups ----------
    const int quad = w & 3;       // output quadrant
    const int kh   = w >> 2;      // K-half: 0 -> K 0..255, 1 -> K 256..511
    const int wr   = (quad >> 1) * 32;
    const int wc   = (quad & 1) * 32;

    f32x4 acc[2][2];
#pragma unroll
    for (int mi = 0; mi < 2; mi++)
#pragma unroll
        for (int ni = 0; ni < 2; ni++)
            acc[mi][ni] = (f32x4){0.f, 0.f, 0.f, 0.f};

#pragma unroll
    for (int j = 0; j < 8; j++) {
        const int kk   = kh * 8 + j;
        const int slot = kk * 4 + (lane >> 4);
        short8 a[2], b[2];
#pragma unroll
        for (int mi = 0; mi < 2; mi++) {
            const int r = wr + mi * 16 + (lane & 15);
            a[mi] = *(const short8*)(As + r * F_DIM + ((slot ^ (r & 7)) << 3));
        }
#pragma unroll
        for (int ni = 0; ni < 2; ni++) {
            const int r = wc + ni * 16 + (lane & 15);
            b[ni] = *(const short8*)(Bs + r * F_DIM + ((slot ^ (r & 7)) << 3));
        }
#pragma unroll
        for (int mi = 0; mi < 2; mi++)
#pragma unroll
            for (int ni = 0; ni < 2; ni++)
                acc[mi][ni] = __builtin_amdgcn_mfma_f32_16x16x32_bf16(
                    a[mi], b[ni], acc[mi][ni], 0, 0, 0);
    }

    // ---------------- Split-K combine via padded LDS (reuse As) ----------
    // Region per quadrant: 64 lanes x 17 floats (stride-17 pad -> no 2^k
    // bank alignment). Waves 4-7 write, barrier, waves 0-3 add.
    __syncthreads();  // all ds_reads of As/Bs done before aliasing As
    float* red = (float*)As;
    if (kh == 1) {
#pragma unroll
        for (int mi = 0; mi < 2; mi++)
#pragma unroll
            for (int ni = 0; ni < 2; ni++)
#pragma unroll
                for (int j = 0; j < 4; j++)
                    red[quad * 1088 + lane * 17 + mi * 8 + ni * 4 + j] =
                        acc[mi][ni][j];
    }
    __syncthreads();
    if (kh == 0) {
#pragma unroll
        for (int mi = 0; mi < 2; mi++)
#pragma unroll
            for (int ni = 0; ni < 2; ni++)
#pragma unroll
                for (int j = 0; j < 4; j++)
                    acc[mi][ni][j] +=
                        red[quad * 1088 + lane * 17 + mi * 8 + ni * 4 + j];

        // ---------------- Epilogue: out = 2*acc - |x|^2 - |m|^2 ----------
        // C/D layout: col = lane&15, row = (lane>>4)*4 + j.
        float xn[2][4];
#pragma unroll
        for (int mi = 0; mi < 2; mi++)
#pragma unroll
            for (int j = 0; j < 4; j++)
                xn[mi][j] = xn_s[wr + mi * 16 + (lane >> 4) * 4 + j];

#pragma unroll
        for (int ni = 0; ni < 2; ni++) {
            const int cl = wc + ni * 16 + (lane & 15);
            const int c  = colBase + cl;
            const float mn = mn_s[cl];
#pragma unroll
            for (int mi = 0; mi < 2; mi++) {
                const int rbase = rowBase + wr + mi * 16 + (lane >> 4) * 4;
#pragma unroll
                for (int j = 0; j < 4; j++)
                    out[(size_t)(rbase + j) * C_ROWS + c] =
                        2.0f * acc[mi][ni][j] - xn[mi][j] - mn;
            }
        }
    }
}

extern "C" void kernel_launch(void* const* d_in, const int* in_sizes, int n_in,
                              void* d_out, int out_size, void* d_ws, size_t ws_size,
                              hipStream_t stream) {
    const float* x     = (const float*)d_in[0];
    const float* means = (const float*)d_in[1];
    float* out = (float*)d_out;
    ncm_fused<<<256, 512, 0, stream>>>(x, means, out);
}